// Round 12
// baseline (483.073 us; speedup 1.0000x reference)
//
#include <hip/hip_runtime.h>
#include <hip/hip_bf16.h>

// Problem constants (fixed by the reference file)
#define BB   32      // batch
#define TT   512     // time
#define II   128     // input dim
#define HH   128     // hidden per rnn
#define NR   16      // num independent rnn blocks
#define HTOT 2048    // HH * NR

typedef __attribute__((ext_vector_type(8))) short short8;   // 8 bf16 (4 VGPR) MFMA A/B frag
typedef __attribute__((ext_vector_type(4))) float f32x4;    // MFMA C/D frag

static __device__ __forceinline__ short f2bf(float f) {
    union { __hip_bfloat16 h; short s; } u;
    u.h = __float2bfloat16(f);
    return u.s;
}
static __device__ __forceinline__ float bf2f(unsigned short u) {
    return __uint_as_float(((unsigned int)u) << 16);
}

// ---------------------------------------------------------------------------
// Kernel 1 (unchanged, known good):
// pre = x @ W_ih^T + b_ih + b_hh, bf16 to ws, layout pre[(n*2+g)][t][m][j].
// ---------------------------------------------------------------------------
__global__ __launch_bounds__(512, 2) void msml_pre(
    const float* __restrict__ x,     // (B,T,I)
    const float* __restrict__ Wih,   // (HTOT, II)
    const float* __restrict__ bih,
    const float* __restrict__ bhh,
    unsigned short* __restrict__ pre)
{
    const int mx = blockIdx.x;      // 0..127
    const int n  = blockIdx.y;      // 0..15
    const int tid = threadIdx.x;
    const int w = tid >> 6, l = tid & 63;
    const int q = l >> 4;
    const int r0 = mx * 128;
    const int b  = r0 >> 9;
    const int t0 = r0 & 511;
    const int g  = b >> 4, m = b & 15;

    __shared__ short A[128 * 136];

    {
        const int row = tid >> 2, cb = tid & 3;
        const float4* xs = reinterpret_cast<const float4*>(x + (size_t)(r0 + row) * II + cb * 32);
        short* dst = &A[row * 136 + cb * 32];
#pragma unroll
        for (int i = 0; i < 8; ++i) {
            float4 v = xs[i];
            *reinterpret_cast<short4*>(dst + 4 * i) =
                make_short4(f2bf(v.x), f2bf(v.y), f2bf(v.z), f2bf(v.w));
        }
    }

    const int j = w * 16 + (l & 15);
    short8 bw[4];
    {
        const float* wb = Wih + (size_t)(n * HH + j) * II + q * 8;
#pragma unroll
        for (int kt = 0; kt < 4; ++kt) {
            float4 u0 = *reinterpret_cast<const float4*>(wb + kt * 32);
            float4 u1 = *reinterpret_cast<const float4*>(wb + kt * 32 + 4);
            short8 s;
            s[0] = f2bf(u0.x); s[1] = f2bf(u0.y); s[2] = f2bf(u0.z); s[3] = f2bf(u0.w);
            s[4] = f2bf(u1.x); s[5] = f2bf(u1.y); s[6] = f2bf(u1.z); s[7] = f2bf(u1.w);
            bw[kt] = s;
        }
    }
    const float bias = bih[n * HH + j] + bhh[n * HH + j];
    __syncthreads();

    const size_t ng = (size_t)(n * 2 + g);
#pragma unroll
    for (int mt = 0; mt < 8; ++mt) {
        const short* ap = &A[(mt * 16 + (l & 15)) * 136 + q * 8];
        f32x4 acc = {0.f, 0.f, 0.f, 0.f};
#pragma unroll
        for (int kt = 0; kt < 4; ++kt) {
            short8 a = *reinterpret_cast<const short8*>(ap + kt * 32);
            acc = __builtin_amdgcn_mfma_f32_16x16x32_bf16(a, bw[kt], acc, 0, 0, 0);
        }
#pragma unroll
        for (int r = 0; r < 4; ++r) {
            const int t = t0 + mt * 16 + q * 4 + r;
            pre[((ng * TT + t) * 16 + m) * 128 + j] = (unsigned short)f2bf(acc[r] + bias);
        }
    }
}

// ---------------------------------------------------------------------------
// Kernel 2: barrier-free single-wave recurrence, named-register build.
// One wave per (n, batch-group g of 16): 32 WGs x 64 threads. All 16 MFMA
// B-cols = real batches (no masking). A = full Wn in 32 NAMED short8 regs
// (no arrays -> no scratch, the r10 failure). Step: unpack pre[t] seeds ->
// issue pre[t+2] loads -> 32 MFMA (kt-major, dep distance 8) -> per-tile
// relu/pack -> uint2 LDS write + float4 out store -> 4x ds_read_b128 of H_t.
// Same-wave DS ordering replaces all barriers. LDS stride 136 shorts:
// reads uniform 8-deep (optimal), writes 2-way (free).
// ---------------------------------------------------------------------------
#define MFMA16 __builtin_amdgcn_mfma_f32_16x16x32_bf16

__global__ __launch_bounds__(64, 1) void msml_recur1w16(
    const float* __restrict__ Whh,            // (HTOT, HTOT)
    const unsigned short* __restrict__ pre,   // bf16 (NR*2, TT, 16, 128)
    float* __restrict__ out)
{
    const int n = blockIdx.x;   // 0..15
    const int g = blockIdx.y;   // 0..1
    const int l = threadIdx.x;  // 0..63
    const int m = l & 15;       // batch (B col / D col); also A row-within-tile
    const int q = l >> 4;       // 0..3 (k-group / D row-group)

    __shared__ short Hs[16 * 136];   // H[batch m][k], row stride 136 shorts

    // ---- stationary A: 32 NAMED frags wfIT_KT = Wn[IT*16+m][KT*32+q*8..+7] ----
    short8 wf0_0, wf0_1, wf0_2, wf0_3, wf1_0, wf1_1, wf1_2, wf1_3;
    short8 wf2_0, wf2_1, wf2_2, wf2_3, wf3_0, wf3_1, wf3_2, wf3_3;
    short8 wf4_0, wf4_1, wf4_2, wf4_3, wf5_0, wf5_1, wf5_2, wf5_3;
    short8 wf6_0, wf6_1, wf6_2, wf6_3, wf7_0, wf7_1, wf7_2, wf7_3;

#define WF_LOAD(IT, KT)                                                        \
    {                                                                          \
        const float* wp = Whh + (size_t)(n * HH + IT * 16 + m) * HTOT          \
                          + n * HH + KT * 32 + q * 8;                          \
        float4 u0 = *reinterpret_cast<const float4*>(wp);                      \
        float4 u1 = *reinterpret_cast<const float4*>(wp + 4);                  \
        short8 s;                                                              \
        s[0]=f2bf(u0.x); s[1]=f2bf(u0.y); s[2]=f2bf(u0.z); s[3]=f2bf(u0.w);    \
        s[4]=f2bf(u1.x); s[5]=f2bf(u1.y); s[6]=f2bf(u1.z); s[7]=f2bf(u1.w);    \
        wf##IT##_##KT = s;                                                     \
    }
    WF_LOAD(0,0) WF_LOAD(0,1) WF_LOAD(0,2) WF_LOAD(0,3)
    WF_LOAD(1,0) WF_LOAD(1,1) WF_LOAD(1,2) WF_LOAD(1,3)
    WF_LOAD(2,0) WF_LOAD(2,1) WF_LOAD(2,2) WF_LOAD(2,3)
    WF_LOAD(3,0) WF_LOAD(3,1) WF_LOAD(3,2) WF_LOAD(3,3)
    WF_LOAD(4,0) WF_LOAD(4,1) WF_LOAD(4,2) WF_LOAD(4,3)
    WF_LOAD(5,0) WF_LOAD(5,1) WF_LOAD(5,2) WF_LOAD(5,3)
    WF_LOAD(6,0) WF_LOAD(6,1) WF_LOAD(6,2) WF_LOAD(6,3)
    WF_LOAD(7,0) WF_LOAD(7,1) WF_LOAD(7,2) WF_LOAD(7,3)
#undef WF_LOAD

    // ---- bases ----
    const unsigned short* pb = pre + (size_t)(n * 2 + g) * TT * 2048 + m * 128 + q * 4;
    float* ob = out + (size_t)(g * 16 + m) * TT * HTOT + n * HH + q * 4;
    float* oh = out + (size_t)BB * TT * HTOT + (size_t)(g * 16 + m) * HTOT + n * HH + q * 4;

    // ---- 2-deep pre prefetch in NAMED regs; h_{-1} = 0 in regs ----
    ushort4 pA0, pA1, pA2, pA3, pA4, pA5, pA6, pA7;
    ushort4 pB0, pB1, pB2, pB3, pB4, pB5, pB6, pB7;
    pA0 = *reinterpret_cast<const ushort4*>(pb);
    pA1 = *reinterpret_cast<const ushort4*>(pb + 16);
    pA2 = *reinterpret_cast<const ushort4*>(pb + 32);
    pA3 = *reinterpret_cast<const ushort4*>(pb + 48);
    pA4 = *reinterpret_cast<const ushort4*>(pb + 64);
    pA5 = *reinterpret_cast<const ushort4*>(pb + 80);
    pA6 = *reinterpret_cast<const ushort4*>(pb + 96);
    pA7 = *reinterpret_cast<const ushort4*>(pb + 112);
    pB0 = *reinterpret_cast<const ushort4*>(pb + 2048);
    pB1 = *reinterpret_cast<const ushort4*>(pb + 2048 + 16);
    pB2 = *reinterpret_cast<const ushort4*>(pb + 2048 + 32);
    pB3 = *reinterpret_cast<const ushort4*>(pb + 2048 + 48);
    pB4 = *reinterpret_cast<const ushort4*>(pb + 2048 + 64);
    pB5 = *reinterpret_cast<const ushort4*>(pb + 2048 + 80);
    pB6 = *reinterpret_cast<const ushort4*>(pb + 2048 + 96);
    pB7 = *reinterpret_cast<const ushort4*>(pb + 2048 + 112);

    const short8 zs = {0, 0, 0, 0, 0, 0, 0, 0};
    short8 hf0 = zs, hf1 = zs, hf2 = zs, hf3 = zs;

#define UNPK(P, A) { A[0]=bf2f(P.x); A[1]=bf2f(P.y); A[2]=bf2f(P.z); A[3]=bf2f(P.w); }

#define EPI(IT, AV, TCUR)                                                      \
    {                                                                          \
        float h0 = fmaxf(AV[0], 0.f), h1 = fmaxf(AV[1], 0.f);                  \
        float h2 = fmaxf(AV[2], 0.f), h3 = fmaxf(AV[3], 0.f);                  \
        unsigned int u0 = (unsigned int)(unsigned short)f2bf(h0) |             \
                          ((unsigned int)(unsigned short)f2bf(h1) << 16);      \
        unsigned int u1 = (unsigned int)(unsigned short)f2bf(h2) |             \
                          ((unsigned int)(unsigned short)f2bf(h3) << 16);      \
        *reinterpret_cast<uint2*>(&Hs[m * 136 + IT * 16 + q * 4]) =            \
            make_uint2(u0, u1);                                                \
        float4 hv = make_float4(h0, h1, h2, h3);                               \
        *reinterpret_cast<float4*>(ob + (size_t)(TCUR) * HTOT + IT * 16) = hv; \
        if ((TCUR) == TT - 1)                                                  \
            *reinterpret_cast<float4*>(oh + IT * 16) = hv;                     \
    }

#define STEP(P0,P1,P2,P3,P4,P5,P6,P7, TCUR)                                    \
    {                                                                          \
        f32x4 a0, a1, a2, a3, a4, a5, a6, a7;                                  \
        UNPK(P0, a0) UNPK(P1, a1) UNPK(P2, a2) UNPK(P3, a3)                    \
        UNPK(P4, a4) UNPK(P5, a5) UNPK(P6, a6) UNPK(P7, a7)                    \
        /* issue pre loads for t+2 (in flight across ~2 steps) */              \
        {                                                                      \
            const int tn = ((TCUR) + 2 < TT) ? (TCUR) + 2 : TT - 1;            \
            const unsigned short* pp = pb + (size_t)tn * 2048;                 \
            P0 = *reinterpret_cast<const ushort4*>(pp);                        \
            P1 = *reinterpret_cast<const ushort4*>(pp + 16);                   \
            P2 = *reinterpret_cast<const ushort4*>(pp + 32);                   \
            P3 = *reinterpret_cast<const ushort4*>(pp + 48);                   \
            P4 = *reinterpret_cast<const ushort4*>(pp + 64);                   \
            P5 = *reinterpret_cast<const ushort4*>(pp + 80);                   \
            P6 = *reinterpret_cast<const ushort4*>(pp + 96);                   \
            P7 = *reinterpret_cast<const ushort4*>(pp + 112);                  \
        }                                                                      \
        /* 32 MFMA, kt-major: dep distance 8 per tile-chain */                 \
        a0 = MFMA16(wf0_0, hf0, a0, 0,0,0); a1 = MFMA16(wf1_0, hf0, a1, 0,0,0);\
        a2 = MFMA16(wf2_0, hf0, a2, 0,0,0); a3 = MFMA16(wf3_0, hf0, a3, 0,0,0);\
        a4 = MFMA16(wf4_0, hf0, a4, 0,0,0); a5 = MFMA16(wf5_0, hf0, a5, 0,0,0);\
        a6 = MFMA16(wf6_0, hf0, a6, 0,0,0); a7 = MFMA16(wf7_0, hf0, a7, 0,0,0);\
        a0 = MFMA16(wf0_1, hf1, a0, 0,0,0); a1 = MFMA16(wf1_1, hf1, a1, 0,0,0);\
        a2 = MFMA16(wf2_1, hf1, a2, 0,0,0); a3 = MFMA16(wf3_1, hf1, a3, 0,0,0);\
        a4 = MFMA16(wf4_1, hf1, a4, 0,0,0); a5 = MFMA16(wf5_1, hf1, a5, 0,0,0);\
        a6 = MFMA16(wf6_1, hf1, a6, 0,0,0); a7 = MFMA16(wf7_1, hf1, a7, 0,0,0);\
        a0 = MFMA16(wf0_2, hf2, a0, 0,0,0); a1 = MFMA16(wf1_2, hf2, a1, 0,0,0);\
        a2 = MFMA16(wf2_2, hf2, a2, 0,0,0); a3 = MFMA16(wf3_2, hf2, a3, 0,0,0);\
        a4 = MFMA16(wf4_2, hf2, a4, 0,0,0); a5 = MFMA16(wf5_2, hf2, a5, 0,0,0);\
        a6 = MFMA16(wf6_2, hf2, a6, 0,0,0); a7 = MFMA16(wf7_2, hf2, a7, 0,0,0);\
        a0 = MFMA16(wf0_3, hf3, a0, 0,0,0); a1 = MFMA16(wf1_3, hf3, a1, 0,0,0);\
        a2 = MFMA16(wf2_3, hf3, a2, 0,0,0); a3 = MFMA16(wf3_3, hf3, a3, 0,0,0);\
        a4 = MFMA16(wf4_3, hf3, a4, 0,0,0); a5 = MFMA16(wf5_3, hf3, a5, 0,0,0);\
        a6 = MFMA16(wf6_3, hf3, a6, 0,0,0); a7 = MFMA16(wf7_3, hf3, a7, 0,0,0);\
        /* per-tile epilogue: relu, pack, LDS uint2 write, out float4 */       \
        EPI(0, a0, TCUR) EPI(1, a1, TCUR) EPI(2, a2, TCUR) EPI(3, a3, TCUR)    \
        EPI(4, a4, TCUR) EPI(5, a5, TCUR) EPI(6, a6, TCUR) EPI(7, a7, TCUR)    \
        /* same-wave readback of H_t (DS in-order; compiler adds lgkm) */     \
        hf0 = *reinterpret_cast<const short8*>(&Hs[m * 136 +  0 + q * 8]);     \
        hf1 = *reinterpret_cast<const short8*>(&Hs[m * 136 + 32 + q * 8]);     \
        hf2 = *reinterpret_cast<const short8*>(&Hs[m * 136 + 64 + q * 8]);     \
        hf3 = *reinterpret_cast<const short8*>(&Hs[m * 136 + 96 + q * 8]);     \
    }

    for (int t = 0; t < TT; t += 2) {
        STEP(pA0, pA1, pA2, pA3, pA4, pA5, pA6, pA7, t)
        STEP(pB0, pB1, pB2, pB3, pB4, pB5, pB6, pB7, t + 1)
    }
#undef STEP
#undef EPI
#undef UNPK
}

// ---------------------------------------------------------------------------
// Fallback (round-2 kernel, known-good): used if ws_size is too small.
// ---------------------------------------------------------------------------
__global__ __launch_bounds__(512, 4) void msml_fused2(
    const float* __restrict__ x,
    const float* __restrict__ Wih,
    const float* __restrict__ Whh,
    const float* __restrict__ bih,
    const float* __restrict__ bhh,
    float* __restrict__ out)
{
    const int n    = blockIdx.x;
    const int b    = blockIdx.y;
    const int tid  = threadIdx.x;
    const int wave = tid >> 6;
    const int lane = tid & 63;
    const int s    = lane >> 4;
    const int j    = wave * 16 + (lane & 15);
    const int row  = n * HH + j;

    float wih[32], whh[32];
    {
        const float4* wi4 = reinterpret_cast<const float4*>(Wih + (size_t)row * II);
        const float4* wh4 = reinterpret_cast<const float4*>(Whh + (size_t)row * HTOT + n * HH);
#pragma unroll
        for (int k = 0; k < 8; ++k) {
            float4 a = wi4[4 * k + s];
            wih[4*k+0] = a.x; wih[4*k+1] = a.y; wih[4*k+2] = a.z; wih[4*k+3] = a.w;
            float4 c = wh4[4 * k + s];
            whh[4*k+0] = c.x; whh[4*k+1] = c.y; whh[4*k+2] = c.z; whh[4*k+3] = c.w;
        }
    }
    const float bias0 = (s == 0) ? (bih[row] + bhh[row]) : 0.0f;

    __shared__ float hs[2][HH];
    if (tid < HH) hs[0][tid] = 0.0f;

    const float* xrow = x + (size_t)b * TT * II;
    float* orow = out + (size_t)b * TT * HTOT + (size_t)n * HH + j;

    float accx;
    {
        const float4* xv = reinterpret_cast<const float4*>(xrow);
        float a0 = bias0, a1 = 0.f, a2 = 0.f, a3 = 0.f;
#pragma unroll
        for (int k = 0; k < 8; ++k) {
            float4 v = xv[4 * k + s];
            a0 += wih[4*k+0] * v.x; a1 += wih[4*k+1] * v.y;
            a2 += wih[4*k+2] * v.z; a3 += wih[4*k+3] * v.w;
        }
        accx = (a0 + a1) + (a2 + a3);
    }
    __syncthreads();

    float hn = 0.0f;
    int buf = 0;
    for (int t = 0; t < TT; ++t) {
        float4 xn[8];
        if (t + 1 < TT) {
            const float4* xv = reinterpret_cast<const float4*>(xrow + (size_t)(t + 1) * II);
#pragma unroll
            for (int k = 0; k < 8; ++k) xn[k] = xv[4 * k + s];
        }
        const float4* hv = reinterpret_cast<const float4*>(hs[buf]);
        float a0 = accx, a1 = 0.f, a2 = 0.f, a3 = 0.f;
#pragma unroll
        for (int k = 0; k < 8; ++k) {
            float4 v = hv[4 * k + s];
            a0 += whh[4*k+0] * v.x; a1 += whh[4*k+1] * v.y;
            a2 += whh[4*k+2] * v.z; a3 += whh[4*k+3] * v.w;
        }
        float sum = (a0 + a1) + (a2 + a3);
        sum += __shfl_xor(sum, 16);
        sum += __shfl_xor(sum, 32);
        hn = fmaxf(sum, 0.0f);

        if (s == 0) {
            orow[(size_t)t * HTOT] = hn;
            hs[buf ^ 1][j] = hn;
        }
        {
            float b0 = bias0, b1 = 0.f, b2 = 0.f, b3 = 0.f;
#pragma unroll
            for (int k = 0; k < 8; ++k) {
                b0 += wih[4*k+0] * xn[k].x; b1 += wih[4*k+1] * xn[k].y;
                b2 += wih[4*k+2] * xn[k].z; b3 += wih[4*k+3] * xn[k].w;
            }
            accx = (b0 + b1) + (b2 + b3);
        }
        buf ^= 1;
        __syncthreads();
    }

    if (s == 0)
        out[(size_t)BB * TT * HTOT + (size_t)b * HTOT + row] = hn;
}

extern "C" void kernel_launch(void* const* d_in, const int* in_sizes, int n_in,
                              void* d_out, int out_size, void* d_ws, size_t ws_size,
                              hipStream_t stream) {
    const float* x   = (const float*)d_in[0];
    const float* Wih = (const float*)d_in[1];
    const float* Whh = (const float*)d_in[2];
    const float* bih = (const float*)d_in[3];
    const float* bhh = (const float*)d_in[4];
    float* out = (float*)d_out;

    const size_t pre_bytes = (size_t)NR * 2 * TT * 16 * 128 * sizeof(unsigned short); // 64 MiB

    if (ws_size >= pre_bytes && d_ws != nullptr) {
        unsigned short* pre = (unsigned short*)d_ws;
        msml_pre<<<dim3(128, NR), 512, 0, stream>>>(x, Wih, bih, bhh, pre);
        msml_recur1w16<<<dim3(NR, 2), 64, 0, stream>>>(Whh, pre, out);
    } else {
        msml_fused2<<<dim3(NR, BB), 512, 0, stream>>>(x, Wih, Whh, bih, bhh, out);
    }
}

// Round 13
// 467.186 us; speedup vs baseline: 1.0340x; 1.0340x over previous
//
#include <hip/hip_runtime.h>
#include <hip/hip_bf16.h>

// Problem constants (fixed by the reference file)
#define BB   32      // batch
#define TT   512     // time
#define II   128     // input dim
#define HH   128     // hidden per rnn
#define NR   16      // num independent rnn blocks
#define HTOT 2048    // HH * NR

typedef __attribute__((ext_vector_type(8))) short short8;   // 8 bf16 (4 VGPR) MFMA A/B frag
typedef __attribute__((ext_vector_type(4))) float f32x4;    // MFMA C/D frag

static __device__ __forceinline__ short f2bf(float f) {
    union { __hip_bfloat16 h; short s; } u;
    u.h = __float2bfloat16(f);
    return u.s;
}
static __device__ __forceinline__ float bf2f(unsigned short u) {
    return __uint_as_float(((unsigned int)u) << 16);
}

// ---------------------------------------------------------------------------
// Kernel 1 (unchanged, known good):
// pre = x @ W_ih^T + b_ih + b_hh, bf16 to ws, layout pre[(n*2+g)][t][m][j].
// ---------------------------------------------------------------------------
__global__ __launch_bounds__(512, 2) void msml_pre(
    const float* __restrict__ x,     // (B,T,I)
    const float* __restrict__ Wih,   // (HTOT, II)
    const float* __restrict__ bih,
    const float* __restrict__ bhh,
    unsigned short* __restrict__ pre)
{
    const int mx = blockIdx.x;      // 0..127
    const int n  = blockIdx.y;      // 0..15
    const int tid = threadIdx.x;
    const int w = tid >> 6, l = tid & 63;
    const int q = l >> 4;
    const int r0 = mx * 128;
    const int b  = r0 >> 9;
    const int t0 = r0 & 511;
    const int g  = b >> 4, m = b & 15;

    __shared__ short A[128 * 136];

    {
        const int row = tid >> 2, cb = tid & 3;
        const float4* xs = reinterpret_cast<const float4*>(x + (size_t)(r0 + row) * II + cb * 32);
        short* dst = &A[row * 136 + cb * 32];
#pragma unroll
        for (int i = 0; i < 8; ++i) {
            float4 v = xs[i];
            *reinterpret_cast<short4*>(dst + 4 * i) =
                make_short4(f2bf(v.x), f2bf(v.y), f2bf(v.z), f2bf(v.w));
        }
    }

    const int j = w * 16 + (l & 15);
    short8 bw[4];
    {
        const float* wb = Wih + (size_t)(n * HH + j) * II + q * 8;
#pragma unroll
        for (int kt = 0; kt < 4; ++kt) {
            float4 u0 = *reinterpret_cast<const float4*>(wb + kt * 32);
            float4 u1 = *reinterpret_cast<const float4*>(wb + kt * 32 + 4);
            short8 s;
            s[0] = f2bf(u0.x); s[1] = f2bf(u0.y); s[2] = f2bf(u0.z); s[3] = f2bf(u0.w);
            s[4] = f2bf(u1.x); s[5] = f2bf(u1.y); s[6] = f2bf(u1.z); s[7] = f2bf(u1.w);
            bw[kt] = s;
        }
    }
    const float bias = bih[n * HH + j] + bhh[n * HH + j];
    __syncthreads();

    const size_t ng = (size_t)(n * 2 + g);
#pragma unroll
    for (int mt = 0; mt < 8; ++mt) {
        const short* ap = &A[(mt * 16 + (l & 15)) * 136 + q * 8];
        f32x4 acc = {0.f, 0.f, 0.f, 0.f};
#pragma unroll
        for (int kt = 0; kt < 4; ++kt) {
            short8 a = *reinterpret_cast<const short8*>(ap + kt * 32);
            acc = __builtin_amdgcn_mfma_f32_16x16x32_bf16(a, bw[kt], acc, 0, 0, 0);
        }
#pragma unroll
        for (int r = 0; r < 4; ++r) {
            const int t = t0 + mt * 16 + q * 4 + r;
            pre[((ng * TT + t) * 16 + m) * 128 + j] = (unsigned short)f2bf(acc[r] + bias);
        }
    }
}

// ---------------------------------------------------------------------------
// Kernel 2: TWO-CELL recurrence. One WG per n (16 WGs x 512 thr = 8 waves).
// Waves 0-3 serve cell (n, g=0), waves 4-7 serve (n, g=1): each SIMD hosts
// 2 waves from INDEPENDENT cells, so their dependency chains interleave
// across the shared barrier (the latency hiding r8 lacked). Per cell the
// wave body is r8's verified A-stationary layout: wave owns 32 j-cols as
// 2 MFMA tiles, A = Wn rows in regs, B = H^T from LDS (4 shared b128
// reads), D packed as b64 writes (2-way bank = free), pre seeded into the
// MFMA C operand from a 3-deep register prefetch. r7 barrier idiom.
// ---------------------------------------------------------------------------
__global__ __launch_bounds__(512, 2) void msml_recur2c(
    const float* __restrict__ Whh,            // (HTOT, HTOT)
    const unsigned short* __restrict__ pre,   // bf16 (NR*2, TT, 16, 128)
    float* __restrict__ out)
{
    const int n = blockIdx.x;   // 0..15
    const int tid = threadIdx.x;
    const int w = tid >> 6;     // wave 0..7
    const int g = w >> 2;       // cell 0..1
    const int wt = w & 3;       // j-tile pair: cols 32*wt .. 32*wt+31
    const int l = tid & 63;
    const int m = l & 15;       // batch (B col / D col)
    const int q = l >> 4;       // 0..3

    __shared__ short Hs[2][2][16 * 136];   // [dbuf][g][m][k], stride 136

    // ---- stationary A-frags: wf[jt][kt] = Wn[(2wt+jt)*16 + m][kt*32+q*8..+7] ----
    short8 wf[2][4];
#pragma unroll
    for (int jt = 0; jt < 2; ++jt)
#pragma unroll
        for (int kt = 0; kt < 4; ++kt) {
            const float* wp = Whh + (size_t)(n * HH + (2 * wt + jt) * 16 + m) * HTOT
                              + n * HH + kt * 32 + q * 8;
            float4 u0 = *reinterpret_cast<const float4*>(wp);
            float4 u1 = *reinterpret_cast<const float4*>(wp + 4);
            short8 s;
            s[0] = f2bf(u0.x); s[1] = f2bf(u0.y); s[2] = f2bf(u0.z); s[3] = f2bf(u0.w);
            s[4] = f2bf(u1.x); s[5] = f2bf(u1.y); s[6] = f2bf(u1.z); s[7] = f2bf(u1.w);
            wf[jt][kt] = s;
        }

    const short8 zs = {0, 0, 0, 0, 0, 0, 0, 0};
    const f32x4 zero4 = {0.f, 0.f, 0.f, 0.f};

    // pre address: batch m, cols 32wt + jt*16 + q*4 (ushort4); jt offset +16
    const unsigned short* pb = pre + (size_t)(n * 2 + g) * TT * 2048 + m * 128
                               + 32 * wt + q * 4;
    // output base: row b = g*16+m, col n*128 + 32wt + q*4
    float* ob = out + (size_t)(g * 16 + m) * TT * HTOT + n * HH + 32 * wt + q * 4;

    // ---- 3-deep pre prefetch; h_{-1} = 0 in registers ----
    ushort4 pA0 = *reinterpret_cast<const ushort4*>(pb);
    ushort4 pA1 = *reinterpret_cast<const ushort4*>(pb + 16);
    ushort4 pB0 = *reinterpret_cast<const ushort4*>(pb + 2048);
    ushort4 pB1 = *reinterpret_cast<const ushort4*>(pb + 2048 + 16);
    ushort4 pC0 = *reinterpret_cast<const ushort4*>(pb + 2 * 2048);
    ushort4 pC1 = *reinterpret_cast<const ushort4*>(pb + 2 * 2048 + 16);

    short8 hf[4];
#pragma unroll
    for (int kt = 0; kt < 4; ++kt) hf[kt] = zs;

    for (int t = 0; t < TT; ++t) {
        const bool last = (t == TT - 1);

        // ---- issue pre load for t+3 (3 loads in flight per tile) ----
        const int tn = (t + 3 < TT) ? t + 3 : TT - 1;
        ushort4 pD0 = *reinterpret_cast<const ushort4*>(pb + (size_t)tn * 2048);
        ushort4 pD1 = *reinterpret_cast<const ushort4*>(pb + (size_t)tn * 2048 + 16);

        // ---- 4 independent depth-2 MFMA chains (2 per j-tile) ----
        f32x4 c0, c1;
        c0[0] = bf2f(pA0.x); c0[1] = bf2f(pA0.y); c0[2] = bf2f(pA0.z); c0[3] = bf2f(pA0.w);
        c1[0] = bf2f(pA1.x); c1[1] = bf2f(pA1.y); c1[2] = bf2f(pA1.z); c1[3] = bf2f(pA1.w);
        f32x4 a00 = __builtin_amdgcn_mfma_f32_16x16x32_bf16(wf[0][0], hf[0], c0, 0, 0, 0);
        f32x4 a10 = __builtin_amdgcn_mfma_f32_16x16x32_bf16(wf[1][0], hf[0], c1, 0, 0, 0);
        f32x4 a01 = __builtin_amdgcn_mfma_f32_16x16x32_bf16(wf[0][2], hf[2], zero4, 0, 0, 0);
        f32x4 a11 = __builtin_amdgcn_mfma_f32_16x16x32_bf16(wf[1][2], hf[2], zero4, 0, 0, 0);
        a00 = __builtin_amdgcn_mfma_f32_16x16x32_bf16(wf[0][1], hf[1], a00, 0, 0, 0);
        a10 = __builtin_amdgcn_mfma_f32_16x16x32_bf16(wf[1][1], hf[1], a10, 0, 0, 0);
        a01 = __builtin_amdgcn_mfma_f32_16x16x32_bf16(wf[0][3], hf[3], a01, 0, 0, 0);
        a11 = __builtin_amdgcn_mfma_f32_16x16x32_bf16(wf[1][3], hf[3], a11, 0, 0, 0);

        // ---- epilogue per tile: relu, pack bf16 -> LDS b64, fp32x4 -> out ----
        float h00 = fmaxf(a00[0] + a01[0], 0.f);
        float h01 = fmaxf(a00[1] + a01[1], 0.f);
        float h02 = fmaxf(a00[2] + a01[2], 0.f);
        float h03 = fmaxf(a00[3] + a01[3], 0.f);
        float h10 = fmaxf(a10[0] + a11[0], 0.f);
        float h11 = fmaxf(a10[1] + a11[1], 0.f);
        float h12 = fmaxf(a10[2] + a11[2], 0.f);
        float h13 = fmaxf(a10[3] + a11[3], 0.f);

        short* hw = &Hs[t & 1][g][m * 136 + 32 * wt + q * 4];
        {
            unsigned int u0 = (unsigned int)(unsigned short)f2bf(h00) |
                              ((unsigned int)(unsigned short)f2bf(h01) << 16);
            unsigned int u1 = (unsigned int)(unsigned short)f2bf(h02) |
                              ((unsigned int)(unsigned short)f2bf(h03) << 16);
            *reinterpret_cast<uint2*>(hw) = make_uint2(u0, u1);
            unsigned int u2 = (unsigned int)(unsigned short)f2bf(h10) |
                              ((unsigned int)(unsigned short)f2bf(h11) << 16);
            unsigned int u3 = (unsigned int)(unsigned short)f2bf(h12) |
                              ((unsigned int)(unsigned short)f2bf(h13) << 16);
            *reinterpret_cast<uint2*>(hw + 16) = make_uint2(u2, u3);
        }

        float* oo = ob + (size_t)t * HTOT;
        *reinterpret_cast<float4*>(oo)      = make_float4(h00, h01, h02, h03);
        *reinterpret_cast<float4*>(oo + 16) = make_float4(h10, h11, h12, h13);

        if (last) {
            float* hh = out + (size_t)BB * TT * HTOT + (size_t)(g * 16 + m) * HTOT
                        + n * HH + 32 * wt + q * 4;
            *reinterpret_cast<float4*>(hh)      = make_float4(h00, h01, h02, h03);
            *reinterpret_cast<float4*>(hh + 16) = make_float4(h10, h11, h12, h13);
            break;
        }

        // ---- LDS-only barrier (r7-verified idiom, no vmcnt drain) ----
        __builtin_amdgcn_sched_barrier(0);
        asm volatile("s_waitcnt lgkmcnt(0)");
        __builtin_amdgcn_s_barrier();
        __builtin_amdgcn_sched_barrier(0);

        // ---- read own cell's H_t (shared by both j-tiles next step) ----
        const short* hr = &Hs[t & 1][g][m * 136 + q * 8];
#pragma unroll
        for (int kt = 0; kt < 4; ++kt)
            hf[kt] = *reinterpret_cast<const short8*>(hr + kt * 32);

        pA0 = pB0; pA1 = pB1; pB0 = pC0; pB1 = pC1; pC0 = pD0; pC1 = pD1;
    }
}

// ---------------------------------------------------------------------------
// Fallback (round-2 kernel, known-good): used if ws_size is too small.
// ---------------------------------------------------------------------------
__global__ __launch_bounds__(512, 4) void msml_fused2(
    const float* __restrict__ x,
    const float* __restrict__ Wih,
    const float* __restrict__ Whh,
    const float* __restrict__ bih,
    const float* __restrict__ bhh,
    float* __restrict__ out)
{
    const int n    = blockIdx.x;
    const int b    = blockIdx.y;
    const int tid  = threadIdx.x;
    const int wave = tid >> 6;
    const int lane = tid & 63;
    const int s    = lane >> 4;
    const int j    = wave * 16 + (lane & 15);
    const int row  = n * HH + j;

    float wih[32], whh[32];
    {
        const float4* wi4 = reinterpret_cast<const float4*>(Wih + (size_t)row * II);
        const float4* wh4 = reinterpret_cast<const float4*>(Whh + (size_t)row * HTOT + n * HH);
#pragma unroll
        for (int k = 0; k < 8; ++k) {
            float4 a = wi4[4 * k + s];
            wih[4*k+0] = a.x; wih[4*k+1] = a.y; wih[4*k+2] = a.z; wih[4*k+3] = a.w;
            float4 c = wh4[4 * k + s];
            whh[4*k+0] = c.x; whh[4*k+1] = c.y; whh[4*k+2] = c.z; whh[4*k+3] = c.w;
        }
    }
    const float bias0 = (s == 0) ? (bih[row] + bhh[row]) : 0.0f;

    __shared__ float hs[2][HH];
    if (tid < HH) hs[0][tid] = 0.0f;

    const float* xrow = x + (size_t)b * TT * II;
    float* orow = out + (size_t)b * TT * HTOT + (size_t)n * HH + j;

    float accx;
    {
        const float4* xv = reinterpret_cast<const float4*>(xrow);
        float a0 = bias0, a1 = 0.f, a2 = 0.f, a3 = 0.f;
#pragma unroll
        for (int k = 0; k < 8; ++k) {
            float4 v = xv[4 * k + s];
            a0 += wih[4*k+0] * v.x; a1 += wih[4*k+1] * v.y;
            a2 += wih[4*k+2] * v.z; a3 += wih[4*k+3] * v.w;
        }
        accx = (a0 + a1) + (a2 + a3);
    }
    __syncthreads();

    float hn = 0.0f;
    int buf = 0;
    for (int t = 0; t < TT; ++t) {
        float4 xn[8];
        if (t + 1 < TT) {
            const float4* xv = reinterpret_cast<const float4*>(xrow + (size_t)(t + 1) * II);
#pragma unroll
            for (int k = 0; k < 8; ++k) xn[k] = xv[4 * k + s];
        }
        const float4* hv = reinterpret_cast<const float4*>(hs[buf]);
        float a0 = accx, a1 = 0.f, a2 = 0.f, a3 = 0.f;
#pragma unroll
        for (int k = 0; k < 8; ++k) {
            float4 v = hv[4 * k + s];
            a0 += whh[4*k+0] * v.x; a1 += whh[4*k+1] * v.y;
            a2 += whh[4*k+2] * v.z; a3 += whh[4*k+3] * v.w;
        }
        float sum = (a0 + a1) + (a2 + a3);
        sum += __shfl_xor(sum, 16);
        sum += __shfl_xor(sum, 32);
        hn = fmaxf(sum, 0.0f);

        if (s == 0) {
            orow[(size_t)t * HTOT] = hn;
            hs[buf ^ 1][j] = hn;
        }
        {
            float b0 = bias0, b1 = 0.f, b2 = 0.f, b3 = 0.f;
#pragma unroll
            for (int k = 0; k < 8; ++k) {
                b0 += wih[4*k+0] * xn[k].x; b1 += wih[4*k+1] * xn[k].y;
                b2 += wih[4*k+2] * xn[k].z; b3 += wih[4*k+3] * xn[k].w;
            }
            accx = (b0 + b1) + (b2 + b3);
        }
        buf ^= 1;
        __syncthreads();
    }

    if (s == 0)
        out[(size_t)BB * TT * HTOT + (size_t)b * HTOT + row] = hn;
}

extern "C" void kernel_launch(void* const* d_in, const int* in_sizes, int n_in,
                              void* d_out, int out_size, void* d_ws, size_t ws_size,
                              hipStream_t stream) {
    const float* x   = (const float*)d_in[0];
    const float* Wih = (const float*)d_in[1];
    const float* Whh = (const float*)d_in[2];
    const float* bih = (const float*)d_in[3];
    const float* bhh = (const float*)d_in[4];
    float* out = (float*)d_out;

    const size_t pre_bytes = (size_t)NR * 2 * TT * 16 * 128 * sizeof(unsigned short); // 64 MiB

    if (ws_size >= pre_bytes && d_ws != nullptr) {
        unsigned short* pre = (unsigned short*)d_ws;
        msml_pre<<<dim3(128, NR), 512, 0, stream>>>(x, Wih, bih, bhh, pre);
        msml_recur2c<<<dim3(NR), 512, 0, stream>>>(Whh, pre, out);
    } else {
        msml_fused2<<<dim3(NR, BB), 512, 0, stream>>>(x, Wih, Whh, bih, bhh, out);
    }
}

// Round 14
// 210.228 us; speedup vs baseline: 2.2979x; 2.2223x over previous
//
#include <hip/hip_runtime.h>
#include <hip/hip_bf16.h>

// Problem constants (fixed by the reference file)
#define BB   32      // batch
#define TT   512     // time
#define II   128     // input dim
#define HH   128     // hidden per rnn
#define NR   16      // num independent rnn blocks
#define HTOT 2048    // HH * NR

typedef __attribute__((ext_vector_type(8))) short short8;   // 8 bf16 (4 VGPR) MFMA A/B frag
typedef __attribute__((ext_vector_type(4))) float f32x4;    // MFMA C/D frag

static __device__ __forceinline__ short f2bf(float f) {
    union { __hip_bfloat16 h; short s; } u;
    u.h = __float2bfloat16(f);
    return u.s;
}
static __device__ __forceinline__ float bf2f(unsigned short u) {
    return __uint_as_float(((unsigned int)u) << 16);
}

// ---------------------------------------------------------------------------
// Kernel 1 v2: pre = x @ W_ih^T + b_ih + b_hh, bf16 -> ws, layout
// pre[(n*2+g)][t][m][j]. KEY CHANGE vs v1: grid = 256 M-tiles ONLY (64 rows
// each, 1 WG/CU); the n-loop moved INSIDE the workgroup so each x-tile is
// staged to LDS once and reused for all 16 n. v1 staged every x-tile 16x ->
// 128 MB of L3 traffic (= the measured 39us). Now x is read once (8 MB);
// Wih (1 MB) stays L2-hot. Kernel becomes write-bound (~64 MB, ~14us).
// ---------------------------------------------------------------------------
__global__ __launch_bounds__(512, 2) void msml_pre2(
    const float* __restrict__ x,     // (B,T,I)
    const float* __restrict__ Wih,   // (HTOT, II)
    const float* __restrict__ bih,
    const float* __restrict__ bhh,
    unsigned short* __restrict__ pre)
{
    const int mx = blockIdx.x;      // 0..255: 64-row tile of the 16384 (b,t) rows
    const int tid = threadIdx.x;
    const int w = tid >> 6, l = tid & 63;
    const int q = l >> 4;
    const int r0 = mx * 64;
    const int b  = r0 >> 9;         // 8 tiles per batch row-block
    const int t0 = r0 & 511;
    const int g  = b >> 4, m = b & 15;

    __shared__ short A[64 * 136];   // x tile bf16, padded row stride 136

    // ---- stage x tile fp32 -> bf16 LDS (once; reused by all 16 n) ----
    {
        const int row = tid >> 3, cb = tid & 7;          // 64 rows x 8 col-chunks
        const float4* xs = reinterpret_cast<const float4*>(
            x + (size_t)(r0 + row) * II + cb * 16);
        short* dst = &A[row * 136 + cb * 16];
#pragma unroll
        for (int i = 0; i < 4; ++i) {
            float4 v = xs[i];
            *reinterpret_cast<short4*>(dst + 4 * i) =
                make_short4(f2bf(v.x), f2bf(v.y), f2bf(v.z), f2bf(v.w));
        }
    }
    __syncthreads();

    const int j = w * 16 + (l & 15);

    for (int n = 0; n < NR; ++n) {
        // ---- B fragments: Wih rows for this wave's 16 cols (L2-hot) ----
        short8 bw[4];
        {
            const float* wb = Wih + (size_t)(n * HH + j) * II + q * 8;
#pragma unroll
            for (int kt = 0; kt < 4; ++kt) {
                float4 u0 = *reinterpret_cast<const float4*>(wb + kt * 32);
                float4 u1 = *reinterpret_cast<const float4*>(wb + kt * 32 + 4);
                short8 s;
                s[0] = f2bf(u0.x); s[1] = f2bf(u0.y); s[2] = f2bf(u0.z); s[3] = f2bf(u0.w);
                s[4] = f2bf(u1.x); s[5] = f2bf(u1.y); s[6] = f2bf(u1.z); s[7] = f2bf(u1.w);
                bw[kt] = s;
            }
        }
        const float bias = bih[n * HH + j] + bhh[n * HH + j];
        const size_t ng = (size_t)(n * 2 + g);

#pragma unroll
        for (int mt = 0; mt < 4; ++mt) {   // 4 row-tiles of 16 t-rows
            const short* ap = &A[(mt * 16 + (l & 15)) * 136 + q * 8];
            f32x4 acc = {0.f, 0.f, 0.f, 0.f};
#pragma unroll
            for (int kt = 0; kt < 4; ++kt) {
                short8 a = *reinterpret_cast<const short8*>(ap + kt * 32);
                acc = __builtin_amdgcn_mfma_f32_16x16x32_bf16(a, bw[kt], acc, 0, 0, 0);
            }
#pragma unroll
            for (int r = 0; r < 4; ++r) {
                const int t = t0 + mt * 16 + q * 4 + r;
                pre[((ng * TT + t) * 16 + m) * 128 + j] = (unsigned short)f2bf(acc[r] + bias);
            }
        }
    }
}

// ---------------------------------------------------------------------------
// Kernel 2: EXACT round-7 recurrence (best measured: 165us). 32 WGs x 8
// waves; B = Wn rows stationary in regs, A = H frags from LDS (b128,
// stride 136), scalar coalesced stores, 2-step pre prefetch, LDS-only
// barrier (lgkmcnt(0) + raw s_barrier, no vmcnt drain).
// ---------------------------------------------------------------------------
__global__ __launch_bounds__(512, 2) void msml_recur(
    const float* __restrict__ Whh,            // (HTOT, HTOT)
    const unsigned short* __restrict__ pre,   // bf16 (NR*2, TT, 16, 128)
    float* __restrict__ out)
{
    const int n = blockIdx.x;   // 0..15
    const int g = blockIdx.y;   // 0..1
    const int tid = threadIdx.x;
    const int w = tid >> 6, l = tid & 63;
    const int q = l >> 4;               // 0..3
    const int j = w * 16 + (l & 15);    // output col 0..127

    __shared__ short Hl[2][16 * 136];

    // ---- Wn^T B-fragments (diag block of Whh), fp32 -> bf16, regs forever ----
    short8 bw[4];
#pragma unroll
    for (int kt = 0; kt < 4; ++kt) {
        const float* wb = Whh + (size_t)(n * HH + j) * HTOT + n * HH + kt * 32 + q * 8;
        float4 u0 = *reinterpret_cast<const float4*>(wb);
        float4 u1 = *reinterpret_cast<const float4*>(wb + 4);
        short8 s;
        s[0] = f2bf(u0.x); s[1] = f2bf(u0.y); s[2] = f2bf(u0.z); s[3] = f2bf(u0.w);
        s[4] = f2bf(u1.x); s[5] = f2bf(u1.y); s[6] = f2bf(u1.z); s[7] = f2bf(u1.w);
        bw[kt] = s;
    }

    // zero H buffer 0 (h_{-1} = 0)
    for (int i = tid; i < 16 * 136; i += 512) Hl[0][i] = 0;

    // pre base for this thread: rows m = q*4 + r, col j
    const unsigned short* pb = pre + ((size_t)(n * 2 + g) * TT) * 2048 + (q * 4) * 128 + j;
    unsigned short pA0, pA1, pA2, pA3, pB0, pB1, pB2, pB3;
    { const unsigned short* pp = pb;        pA0 = pp[0]; pA1 = pp[128]; pA2 = pp[256]; pA3 = pp[384]; }
    { const unsigned short* pp = pb + 2048; pB0 = pp[0]; pB1 = pp[128]; pB2 = pp[256]; pB3 = pp[384]; }

    const size_t MS = (size_t)TT * HTOT;   // out stride per batch row
    float* ob = out + (size_t)(g * 16 + q * 4) * MS + n * HH + j;

    __syncthreads();   // Hl[0] zeros visible (startup only)

#define RSTEP(HRD, HWR, P0, P1, P2, P3, TCUR)                                      \
    {                                                                              \
        const short* hp = &HRD[(l & 15) * 136 + q * 8];                            \
        f32x4 acc = {0.f, 0.f, 0.f, 0.f};                                          \
        _Pragma("unroll")                                                          \
        for (int kt = 0; kt < 4; ++kt) {                                           \
            short8 a = *reinterpret_cast<const short8*>(hp + kt * 32);             \
            acc = __builtin_amdgcn_mfma_f32_16x16x32_bf16(a, bw[kt], acc, 0, 0, 0);\
        }                                                                          \
        float h0 = fmaxf(acc[0] + bf2f(P0), 0.f);                                  \
        float h1 = fmaxf(acc[1] + bf2f(P1), 0.f);                                  \
        float h2 = fmaxf(acc[2] + bf2f(P2), 0.f);                                  \
        float h3 = fmaxf(acc[3] + bf2f(P3), 0.f);                                  \
        { int tn = (TCUR) + 2 < TT ? (TCUR) + 2 : TT - 1;                          \
          const unsigned short* pp = pb + (size_t)tn * 2048;                       \
          P0 = pp[0]; P1 = pp[128]; P2 = pp[256]; P3 = pp[384]; }                  \
        float* oo = ob + (size_t)(TCUR) * HTOT;                                    \
        oo[0] = h0; oo[MS] = h1; oo[2 * MS] = h2; oo[3 * MS] = h3;                 \
        HWR[(q * 4 + 0) * 136 + j] = f2bf(h0);                                     \
        HWR[(q * 4 + 1) * 136 + j] = f2bf(h1);                                     \
        HWR[(q * 4 + 2) * 136 + j] = f2bf(h2);                                     \
        HWR[(q * 4 + 3) * 136 + j] = f2bf(h3);                                     \
        if ((TCUR) == TT - 1) {                                                    \
            float* hh = out + (size_t)BB * TT * HTOT                               \
                        + (size_t)(g * 16 + q * 4) * HTOT + n * HH + j;            \
            hh[0] = h0; hh[HTOT] = h1; hh[2 * HTOT] = h2; hh[3 * HTOT] = h3;       \
        }                                                                          \
        __builtin_amdgcn_sched_barrier(0);                                         \
        asm volatile("s_waitcnt lgkmcnt(0)");                                      \
        __builtin_amdgcn_s_barrier();                                              \
        __builtin_amdgcn_sched_barrier(0);                                         \
    }

    short* hb0 = &Hl[0][0];
    short* hb1 = &Hl[1][0];
    for (int t = 0; t < TT; t += 2) {
        RSTEP(hb0, hb1, pA0, pA1, pA2, pA3, t)
        RSTEP(hb1, hb0, pB0, pB1, pB2, pB3, t + 1)
    }
#undef RSTEP
}

// ---------------------------------------------------------------------------
// Fallback (round-2 kernel, known-good): used if ws_size is too small.
// ---------------------------------------------------------------------------
__global__ __launch_bounds__(512, 4) void msml_fused2(
    const float* __restrict__ x,
    const float* __restrict__ Wih,
    const float* __restrict__ Whh,
    const float* __restrict__ bih,
    const float* __restrict__ bhh,
    float* __restrict__ out)
{
    const int n    = blockIdx.x;
    const int b    = blockIdx.y;
    const int tid  = threadIdx.x;
    const int wave = tid >> 6;
    const int lane = tid & 63;
    const int s    = lane >> 4;
    const int j    = wave * 16 + (lane & 15);
    const int row  = n * HH + j;

    float wih[32], whh[32];
    {
        const float4* wi4 = reinterpret_cast<const float4*>(Wih + (size_t)row * II);
        const float4* wh4 = reinterpret_cast<const float4*>(Whh + (size_t)row * HTOT + n * HH);
#pragma unroll
        for (int k = 0; k < 8; ++k) {
            float4 a = wi4[4 * k + s];
            wih[4*k+0] = a.x; wih[4*k+1] = a.y; wih[4*k+2] = a.z; wih[4*k+3] = a.w;
            float4 c = wh4[4 * k + s];
            whh[4*k+0] = c.x; whh[4*k+1] = c.y; whh[4*k+2] = c.z; whh[4*k+3] = c.w;
        }
    }
    const float bias0 = (s == 0) ? (bih[row] + bhh[row]) : 0.0f;

    __shared__ float hs[2][HH];
    if (tid < HH) hs[0][tid] = 0.0f;

    const float* xrow = x + (size_t)b * TT * II;
    float* orow = out + (size_t)b * TT * HTOT + (size_t)n * HH + j;

    float accx;
    {
        const float4* xv = reinterpret_cast<const float4*>(xrow);
        float a0 = bias0, a1 = 0.f, a2 = 0.f, a3 = 0.f;
#pragma unroll
        for (int k = 0; k < 8; ++k) {
            float4 v = xv[4 * k + s];
            a0 += wih[4*k+0] * v.x; a1 += wih[4*k+1] * v.y;
            a2 += wih[4*k+2] * v.z; a3 += wih[4*k+3] * v.w;
        }
        accx = (a0 + a1) + (a2 + a3);
    }
    __syncthreads();

    float hn = 0.0f;
    int buf = 0;
    for (int t = 0; t < TT; ++t) {
        float4 xn[8];
        if (t + 1 < TT) {
            const float4* xv = reinterpret_cast<const float4*>(xrow + (size_t)(t + 1) * II);
#pragma unroll
            for (int k = 0; k < 8; ++k) xn[k] = xv[4 * k + s];
        }
        const float4* hv = reinterpret_cast<const float4*>(hs[buf]);
        float a0 = accx, a1 = 0.f, a2 = 0.f, a3 = 0.f;
#pragma unroll
        for (int k = 0; k < 8; ++k) {
            float4 v = hv[4 * k + s];
            a0 += whh[4*k+0] * v.x; a1 += whh[4*k+1] * v.y;
            a2 += whh[4*k+2] * v.z; a3 += whh[4*k+3] * v.w;
        }
        float sum = (a0 + a1) + (a2 + a3);
        sum += __shfl_xor(sum, 16);
        sum += __shfl_xor(sum, 32);
        hn = fmaxf(sum, 0.0f);

        if (s == 0) {
            orow[(size_t)t * HTOT] = hn;
            hs[buf ^ 1][j] = hn;
        }
        {
            float b0 = bias0, b1 = 0.f, b2 = 0.f, b3 = 0.f;
#pragma unroll
            for (int k = 0; k < 8; ++k) {
                b0 += wih[4*k+0] * xn[k].x; b1 += wih[4*k+1] * xn[k].y;
                b2 += wih[4*k+2] * xn[k].z; b3 += wih[4*k+3] * xn[k].w;
            }
            accx = (b0 + b1) + (b2 + b3);
        }
        buf ^= 1;
        __syncthreads();
    }

    if (s == 0)
        out[(size_t)BB * TT * HTOT + (size_t)b * HTOT + row] = hn;
}

extern "C" void kernel_launch(void* const* d_in, const int* in_sizes, int n_in,
                              void* d_out, int out_size, void* d_ws, size_t ws_size,
                              hipStream_t stream) {
    const float* x   = (const float*)d_in[0];
    const float* Wih = (const float*)d_in[1];
    const float* Whh = (const float*)d_in[2];
    const float* bih = (const float*)d_in[3];
    const float* bhh = (const float*)d_in[4];
    float* out = (float*)d_out;

    const size_t pre_bytes = (size_t)NR * 2 * TT * 16 * 128 * sizeof(unsigned short); // 64 MiB

    if (ws_size >= pre_bytes && d_ws != nullptr) {
        unsigned short* pre = (unsigned short*)d_ws;
        msml_pre2<<<dim3(256), 512, 0, stream>>>(x, Wih, bih, bhh, pre);
        msml_recur<<<dim3(NR, 2), 512, 0, stream>>>(Whh, pre, out);
    } else {
        msml_fused2<<<dim3(NR, BB), 512, 0, stream>>>(x, Wih, Whh, bih, bhh, out);
    }
}